// Round 3
// baseline (201.589 us; speedup 1.0000x reference)
//
#include <hip/hip_runtime.h>

typedef unsigned int u32;
typedef unsigned long long u64;

#define NB 32
#define NCLS 80
#define NANCHOR 8400
#define PRE 1000
#define MAXDET 100
#define NT 1024

// ---------------------------------------------------------------------------
// Kernel 1: decode all levels. One thread per (image, 4-anchor quad); all
// global traffic is float4/int4 (16 B/lane). Level extents (6400/1600/400)
// and row lengths (80/40/20) are divisible by 4, so a quad never straddles
// a level or a grid row.
// ---------------------------------------------------------------------------
__global__ void decode_kernel(const float* __restrict__ cls0, const float* __restrict__ box0,
                              const float* __restrict__ cls1, const float* __restrict__ box1,
                              const float* __restrict__ cls2, const float* __restrict__ box2,
                              float* __restrict__ ws_scores, float4* __restrict__ ws_boxes,
                              int* __restrict__ ws_cls) {
    const int NQ = NANCHOR / 4;                 // 2100 quads per image
    int q = blockIdx.x * blockDim.x + threadIdx.x;
    if (q >= NB * NQ) return;
    int b = q / NQ;
    int r = (q - b * NQ) * 4;                   // first anchor of the quad

    const float* cp; const float* bp;
    int HW, hw, rowlen, step;
    if (r < 6400) {
        cp = cls0 + (size_t)b * NCLS * 6400; bp = box0 + (size_t)b * 4 * 6400;
        HW = 6400; hw = r;        rowlen = 80; step = 8;
    } else if (r < 8000) {
        cp = cls1 + (size_t)b * NCLS * 1600; bp = box1 + (size_t)b * 4 * 1600;
        HW = 1600; hw = r - 6400; rowlen = 40; step = 16;
    } else {
        cp = cls2 + (size_t)b * NCLS * 400;  bp = box2 + (size_t)b * 4 * 400;
        HW = 400;  hw = r - 8000; rowlen = 20; step = 32;
    }

    // vectorized argmax over 80 class logits (first-max semantics: strict >)
    float4 m = *(const float4*)(cp + hw);
    int c0 = 0, c1 = 0, c2 = 0, c3 = 0;
    for (int c = 1; c < NCLS; ++c) {
        float4 v = *(const float4*)(cp + (size_t)c * HW + hw);
        if (v.x > m.x) { m.x = v.x; c0 = c; }
        if (v.y > m.y) { m.y = v.y; c1 = c; }
        if (v.z > m.z) { m.z = v.z; c2 = c; }
        if (v.w > m.w) { m.w = v.w; c3 = c; }
    }

    float4 L  = *(const float4*)(bp + hw);
    float4 T  = *(const float4*)(bp + HW + hw);
    float4 R  = *(const float4*)(bp + 2 * HW + hw);
    float4 Bo = *(const float4*)(bp + 3 * HW + hw);

    int h = hw / rowlen, w = hw - h * rowlen;   // w..w+3 stay in this row
    float gy  = (float)(h * step);
    float gx0 = (float)(w * step);
    float gx1 = gx0 + (float)step;
    float gx2 = gx1 + (float)step;
    float gx3 = gx2 + (float)step;

    int g = b * NANCHOR + r;
    float4 sc;
    sc.x = 1.0f / (1.0f + expf(-m.x));
    sc.y = 1.0f / (1.0f + expf(-m.y));
    sc.z = 1.0f / (1.0f + expf(-m.z));
    sc.w = 1.0f / (1.0f + expf(-m.w));
    *(float4*)(ws_scores + g) = sc;
    ws_boxes[g + 0] = make_float4(gx0 - L.x, gy - T.x, gx0 + R.x, gy + Bo.x);
    ws_boxes[g + 1] = make_float4(gx1 - L.y, gy - T.y, gx1 + R.y, gy + Bo.y);
    ws_boxes[g + 2] = make_float4(gx2 - L.z, gy - T.z, gx2 + R.z, gy + Bo.z);
    ws_boxes[g + 3] = make_float4(gx3 - L.w, gy - T.w, gx3 + R.w, gy + Bo.w);
    *(int4*)(ws_cls + g) = make_int4(c0, c1, c2, c3);
}

// ---------------------------------------------------------------------------
// helpers
// ---------------------------------------------------------------------------
__device__ __forceinline__ u64 shfl_xor_u64(u64 v, int m) {
    u32 lo = (u32)v, hi = (u32)(v >> 32);
    lo = (u32)__shfl_xor((int)lo, m, 64);
    hi = (u32)__shfl_xor((int)hi, m, 64);
    return ((u64)hi << 32) | (u64)lo;
}

__device__ __forceinline__ u64 readlane_u64(u64 v, int l) {
    u32 lo = (u32)v, hi = (u32)(v >> 32);
    lo = (u32)__builtin_amdgcn_readlane((int)lo, l);
    hi = (u32)__builtin_amdgcn_readlane((int)hi, l);
    return ((u64)hi << 32) | (u64)lo;
}

// inclusive suffix sum over sh[0..1023]; 3 barriers total.
__device__ __forceinline__ void suffix_scan_1024(int* sh, int* swsum, int* swadd) {
    const int tid = threadIdx.x, lane = tid & 63, wv = tid >> 6;
    int s = sh[tid];
#pragma unroll
    for (int off = 1; off < 64; off <<= 1) {
        int u = __shfl_down(s, off, 64);
        if (lane + off < 64) s += u;
    }
    if (lane == 0) swsum[wv] = s;          // wave total = suffix at lane 0
    __syncthreads();
    if (tid < 64) {
        int t = (lane < 16) ? swsum[lane] : 0;
#pragma unroll
        for (int off = 1; off < 16; off <<= 1) {
            int u = __shfl_down(t, off, 64);
            if (lane + off < 64) t += u;
        }
        int ab = __shfl_down(t, 1, 64);    // suffix of waves strictly above
        if (lane < 16) swadd[lane] = (lane == 15) ? 0 : ab;
    }
    __syncthreads();
    sh[tid] = s + swadd[wv];
    __syncthreads();
}

// ---------------------------------------------------------------------------
// Kernel 2: per-image radix-select + sort. Score bits live in per-thread
// registers (each thread re-reads exactly the elements it loaded: a=tid+k*NT,
// static unrolled indexing). cnt<=1024: single-wave zero-barrier register
// bitonic. cnt>1024 (tie-storm): LDS bitonic fallback on 2048.
// ---------------------------------------------------------------------------
__global__ __launch_bounds__(NT) void select_sort_kernel(
        const float* __restrict__ ws_scores, const float4* __restrict__ ws_boxes,
        const int* __restrict__ ws_cls, u64* __restrict__ ws_keys,
        float* __restrict__ ws_sx1, float* __restrict__ ws_sy1,
        float* __restrict__ ws_sx2, float* __restrict__ ws_sy2,
        float* __restrict__ ws_sar) {
    const int b = blockIdx.x;
    const int tid = threadIdx.x;

    __shared__ int s_hist[1024];
    __shared__ u64 s_key[2048];
    __shared__ int s_wsum[16], s_wadd[16];
    __shared__ int s_C, s_base, s_cnt;
    __shared__ u32 s_thresh;

    const float* sc = ws_scores + (size_t)b * NANCHOR;

    s_hist[tid] = 0;
    s_key[tid] = 0ULL;
    s_key[tid + 1024] = 0ULL;
    if (tid == 0) s_cnt = 0;
    __syncthreads();

    // ---- pass 1: coarse histogram on bits [29:20]; cache bits in registers
    u32 sb[9];
#pragma unroll
    for (int k = 0; k < 9; ++k) {
        int a = tid + k * NT;
        if (a < NANCHOR) {
            u32 x = __float_as_uint(sc[a]);
            sb[k] = x;
            atomicAdd(&s_hist[x >> 20], 1);
        } else sb[k] = 0;
    }
    __syncthreads();
    suffix_scan_1024(s_hist, s_wsum, s_wadd);
    {
        int sfx = s_hist[tid];
        int nxt = (tid < 1023) ? s_hist[tid + 1] : 0;
        if (sfx >= PRE && (tid == 1023 || nxt < PRE)) { s_C = tid; s_base = nxt; }
    }
    __syncthreads();
    const int C = s_C, base = s_base;
    s_hist[tid] = 0;
    __syncthreads();

    // ---- pass 2: fine histogram on bits [19:10] within coarse bin C
#pragma unroll
    for (int k = 0; k < 9; ++k) {
        int a = tid + k * NT;
        if (a < NANCHOR && (int)(sb[k] >> 20) == C)
            atomicAdd(&s_hist[(sb[k] >> 10) & 1023], 1);
    }
    __syncthreads();
    suffix_scan_1024(s_hist, s_wsum, s_wadd);
    {
        int sfx = base + s_hist[tid];
        int nxt = base + ((tid < 1023) ? s_hist[tid + 1] : 0);
        if (sfx >= PRE && (tid == 1023 || nxt < PRE))
            s_thresh = ((u32)C << 20) | ((u32)tid << 10);
    }
    __syncthreads();
    const u32 thresh = s_thresh;

    // ---- compaction
#pragma unroll
    for (int k = 0; k < 9; ++k) {
        int a = tid + k * NT;
        if (a < NANCHOR && sb[k] >= thresh) {
            int pos = atomicAdd(&s_cnt, 1);
            if (pos < 2048)
                s_key[pos] = ((u64)sb[k] << 14) | (u64)(NANCHOR - 1 - a);
        }
    }
    __syncthreads();
    const int cnt = s_cnt;

    if (cnt > 1024) {
        // ---- fallback: LDS bitonic on 2048 (wave-sync for j<=32)
        bool prevBig = false;
        for (int k = 2; k <= 2048; k <<= 1) {
            for (int j = k >> 1; j > 0; j >>= 1) {
                const bool big = (j >= 64);
                if (big || prevBig) __syncthreads();
                else __builtin_amdgcn_wave_barrier();
                for (int i = tid; i < 2048; i += NT) {
                    int ixj = i ^ j;
                    if (ixj > i) {
                        u64 va = s_key[i], vb = s_key[ixj];
                        bool desc = ((i & k) == 0);
                        if (desc ? (va < vb) : (va > vb)) { s_key[i] = vb; s_key[ixj] = va; }
                    }
                }
                prevBig = big;
            }
        }
        __syncthreads();
    } else {
        // ---- single-wave register bitonic over 1024 keys, no barriers
        if (tid < 64) {
            const int lane = tid;
            u64 v[16];
#pragma unroll
            for (int r = 0; r < 16; ++r) v[r] = s_key[(r << 6) | lane];

#define CE_REG(ra, rb, DESC) { u64 a_ = v[(ra)], b_ = v[(rb)];                        \
            if ((DESC) ? (a_ < b_) : (a_ > b_)) { v[(ra)] = b_; v[(rb)] = a_; } }
#define CE_SHFL(rr_, jj_, DESC) { u64 a_ = v[(rr_)]; u64 p_ = shfl_xor_u64(a_, (jj_)); \
            bool up_ = ((lane & (jj_)) == 0); bool km_ = ((DESC) == up_);              \
            bool pg_ = (p_ > a_); v[(rr_)] = (km_ == pg_) ? p_ : a_; }

#pragma unroll
            for (int kl = 1; kl <= 10; ++kl) {
                const int K = 1 << kl;
#pragma unroll
                for (int js = 10; js >= 0; --js) {
                    if (js > kl - 1) continue;
                    const int j = 1 << js;
                    if (j >= 64) {
                        const int jr = j >> 6;
#pragma unroll
                        for (int r = 0; r < 16; ++r) {
                            if ((r & jr) == 0) {
                                const bool desc = ((r & (K >> 6)) == 0);
                                CE_REG(r, r | jr, desc);
                            }
                        }
                    } else {
#pragma unroll
                        for (int r = 0; r < 16; ++r) {
                            if (K >= 64) {
                                const bool desc = ((r & (K >> 6)) == 0);
                                CE_SHFL(r, j, desc);
                            } else {
                                CE_SHFL(r, j, ((lane & K) == 0));
                            }
                        }
                    }
                }
            }
#undef CE_REG
#undef CE_SHFL

#pragma unroll
            for (int r = 0; r < 16; ++r) s_key[(r << 6) | lane] = v[r];
        }
        __syncthreads();
    }

    // ---- write sorted keys + class-offset boxes/areas (slots 0..1023)
    {
        u64 key = s_key[tid];
        ws_keys[(b << 10) + tid] = key;
        int idx = (NANCHOR - 1) - (int)(key & 16383ULL);
        float4 bx = ws_boxes[(size_t)b * NANCHOR + idx];
        int c = ws_cls[(size_t)b * NANCHOR + idx];
        float off = (float)c * 4096.0f;
        float x1 = bx.x + off, y1 = bx.y + off, x2 = bx.z + off, y2 = bx.w + off;
        int o = (b << 10) + tid;
        ws_sx1[o] = x1; ws_sy1[o] = y1; ws_sx2[o] = x2; ws_sy2[o] = y2;
        ws_sar[o] = fmaxf(x2 - x1, 0.0f) * fmaxf(y2 - y1, 0.0f);
    }
}

// ---------------------------------------------------------------------------
// Kernel 3: suppression bitmap. Block = (image, 64-row tile); thread = (row, word).
// bits[r][w] bit k = (IoU(r, w*64+k) > 0.5) && (w*64+k > r) && (w*64+k < 1000).
// Also writes the diagonal word (w == r>>6) to a compact per-row array.
// ---------------------------------------------------------------------------
__global__ __launch_bounds__(1024) void iou_bits_kernel(
        const float* __restrict__ ws_sx1, const float* __restrict__ ws_sy1,
        const float* __restrict__ ws_sx2, const float* __restrict__ ws_sy2,
        const float* __restrict__ ws_sar,
        u64* __restrict__ ws_bits, u64* __restrict__ ws_diag) {
    const int blk = blockIdx.x;
    const int b = blk >> 4, tile = blk & 15;
    const int tid = threadIdx.x;

    __shared__ float sx1[1024], sy1[1024], sx2[1024], sy2[1024], sar[1024];
    {
        int o = (b << 10) + tid;
        sx1[tid] = ws_sx1[o]; sy1[tid] = ws_sy1[o];
        sx2[tid] = ws_sx2[o]; sy2[tid] = ws_sy2[o];
        sar[tid] = ws_sar[o];
    }
    __syncthreads();

    const int rl = tid & 63, w = tid >> 6;
    const int r = (tile << 6) + rl;
    u64 bits = 0ULL;
    if (r < 1000 && w >= tile) {            // words below the diagonal are all-zero
        float xi1 = sx1[r], yi1 = sy1[r], xi2 = sx2[r], yi2 = sy2[r], ai = sar[r];
        const int jbase = w << 6;
#pragma unroll 8
        for (int kb = 0; kb < 64; ++kb) {
            int j = jbase + kb;             // broadcast LDS reads across the wave
            float lx = fmaxf(xi1, sx1[j]);
            float ly = fmaxf(yi1, sy1[j]);
            float rx = fminf(xi2, sx2[j]);
            float ry = fminf(yi2, sy2[j]);
            float wx = fmaxf(rx - lx, 0.0f);
            float wy = fmaxf(ry - ly, 0.0f);
            float inter = wx * wy;
            float iou = inter / (ai + sar[j] - inter + 1e-7f);
            bits |= (iou > 0.5f) ? (1ULL << kb) : 0ULL;
        }
        u64 mlow;                            // keep only j > r
        if (w == tile) {
            int bpos = r & 63;
            mlow = (bpos == 63) ? 0ULL : (~0ULL << (bpos + 1));
        } else mlow = ~0ULL;
        u64 mhigh = (jbase + 64 <= 1000) ? ~0ULL : ((1ULL << (1000 - jbase)) - 1ULL);
        bits &= mlow & mhigh;
    }
    ws_bits[((size_t)b << 14) + ((size_t)r << 4) + w] = bits;
    if (w == tile) ws_diag[(b << 10) + r] = bits;
}

// ---------------------------------------------------------------------------
// Kernel 4: per-image barrier-free greedy scan over the bitmap (wave 0 of a
// 128-thread block), then output.
// ---------------------------------------------------------------------------
__global__ __launch_bounds__(128) void nms_scan_kernel(
        const u64* __restrict__ ws_bits, const u64* __restrict__ ws_diag,
        const u64* __restrict__ ws_keys, const float4* __restrict__ ws_boxes,
        const int* __restrict__ ws_cls, float* __restrict__ out) {
    const int b = blockIdx.x;
    const int tid = threadIdx.x;

    __shared__ int s_keep[MAXDET];
    __shared__ int s_nk;

    if (tid < 64) {
        const int lane = tid;
        const u64* bits = ws_bits + ((size_t)b << 14);
        const u64* diag = ws_diag + ((size_t)b << 10);
        int nkept = 0;
        for (int wi = 0; wi < 16 && nkept < MAXDET; ++wi) {
            const int wbase = wi << 6;
            // state of this word from rows kept in earlier words
            u64 acc = 0ULL;
            if (lane < nkept)       acc  = bits[((size_t)s_keep[lane] << 4) + wi];
            if (lane + 64 < nkept)  acc |= bits[((size_t)s_keep[lane + 64] << 4) + wi];
#pragma unroll
            for (int off = 32; off > 0; off >>= 1) acc |= shfl_xor_u64(acc, off);
            u64 cur = acc;                          // uniform across the wave
            u64 rw = diag[wbase + lane];            // lane l holds word wi of row wbase+l
            const int nb = (wbase + 64 <= 1000) ? 64 : (1000 - wbase);
            for (int bit = 0; bit < nb; ++bit) {
                if (!((cur >> bit) & 1ULL)) {
                    if (lane == 0) s_keep[nkept] = wbase + bit;
                    nkept++;
                    if (nkept >= MAXDET) break;
                    cur |= readlane_u64(rw, bit);   // suppress within this word
                }
            }
        }
        if (lane == 0) s_nk = nkept;
    }
    __syncthreads();

    const int nk = s_nk;
    if (tid < MAXDET) {
        float* o = out + ((size_t)b * MAXDET + tid) * 5;
        float* oc = out + (size_t)NB * MAXDET * 5 + (size_t)b * MAXDET + tid;
        if (tid < nk) {
            int rank = s_keep[tid];
            u64 key = ws_keys[(b << 10) + rank];
            int idx = (NANCHOR - 1) - (int)(key & 16383ULL);
            float score = __uint_as_float((u32)(key >> 14));
            float4 bx = ws_boxes[(size_t)b * NANCHOR + idx];
            int c = ws_cls[(size_t)b * NANCHOR + idx];
            o[0] = bx.x; o[1] = bx.y; o[2] = bx.z; o[3] = bx.w; o[4] = score;
            *oc = (float)c;
        } else {
            o[0] = 0.0f; o[1] = 0.0f; o[2] = 0.0f; o[3] = 0.0f; o[4] = 0.0f;
            *oc = -1.0f;
        }
    }
}

extern "C" void kernel_launch(void* const* d_in, const int* in_sizes, int n_in,
                              void* d_out, int out_size, void* d_ws, size_t ws_size,
                              hipStream_t stream) {
    const float* cls0 = (const float*)d_in[0];
    const float* box0 = (const float*)d_in[1];
    const float* cls1 = (const float*)d_in[2];
    const float* box1 = (const float*)d_in[3];
    const float* cls2 = (const float*)d_in[4];
    const float* box2 = (const float*)d_in[5];

    float* ws = (float*)d_ws;
    float* ws_scores = ws;                                    // 268800 f32
    float4* ws_boxes = (float4*)(ws + NB * NANCHOR);          // 268800 float4
    int* ws_cls = (int*)(ws + (size_t)NB * NANCHOR * 5);      // 268800 int
    float* base6 = ws + (size_t)NB * NANCHOR * 6;             // byte 6,451,200
    u64* ws_keys = (u64*)base6;                               // 32*1024 u64
    float* ws_sx1 = base6 + 65536;                            // after 262144 B
    float* ws_sy1 = ws_sx1 + NB * 1024;
    float* ws_sx2 = ws_sy1 + NB * 1024;
    float* ws_sy2 = ws_sx2 + NB * 1024;
    float* ws_sar = ws_sy2 + NB * 1024;
    u64* ws_bits = (u64*)(ws_sar + NB * 1024);                // 32*1024*16 u64 = 4 MB
    u64* ws_diag = ws_bits + (size_t)NB * 1024 * 16;          // 32*1024 u64

    int totalq = NB * (NANCHOR / 4);
    decode_kernel<<<(totalq + 255) / 256, 256, 0, stream>>>(
        cls0, box0, cls1, box1, cls2, box2, ws_scores, ws_boxes, ws_cls);

    select_sort_kernel<<<NB, NT, 0, stream>>>(ws_scores, ws_boxes, ws_cls, ws_keys,
                                              ws_sx1, ws_sy1, ws_sx2, ws_sy2, ws_sar);

    iou_bits_kernel<<<NB * 16, 1024, 0, stream>>>(ws_sx1, ws_sy1, ws_sx2, ws_sy2, ws_sar,
                                                  ws_bits, ws_diag);

    nms_scan_kernel<<<NB, 128, 0, stream>>>(ws_bits, ws_diag, ws_keys, ws_boxes, ws_cls,
                                            (float*)d_out);
}

// Round 4
// 185.667 us; speedup vs baseline: 1.0858x; 1.0858x over previous
//
#include <hip/hip_runtime.h>

typedef unsigned int u32;
typedef unsigned long long u64;

#define NB 32
#define NCLS 80
#define NANCHOR 8400
#define PRE 1000
#define MAXDET 100
#define NT 1024

// ---------------------------------------------------------------------------
// Kernel 1: decode all levels. Block = 64 quads (256 anchors); the 4 waves of
// the block split the 80-class argmax into 20-class slices (wave w -> classes
// [20w,20w+20)), each lane owning one quad with float4 (16 B) loads. Partials
// reduce through LDS; wave 0 finishes (sigmoid + box decode + stores).
// Grid = 1050 blocks -> ~4 blocks/CU, so HBM latency is TLP-hidden.
// ---------------------------------------------------------------------------
__global__ __launch_bounds__(256) void decode_kernel(
        const float* __restrict__ cls0, const float* __restrict__ box0,
        const float* __restrict__ cls1, const float* __restrict__ box1,
        const float* __restrict__ cls2, const float* __restrict__ box2,
        float* __restrict__ ws_scores, float4* __restrict__ ws_boxes,
        int* __restrict__ ws_cls) {
    const int NQ = NANCHOR / 4;                 // 2100 quads per image
    const int lane = threadIdx.x & 63;
    const int wv = threadIdx.x >> 6;            // class slice 0..3
    const int q = blockIdx.x * 64 + lane;       // quad id (grid is exact: 1050*64)
    int b = q / NQ;
    int r = (q - b * NQ) * 4;                   // first anchor of the quad

    const float* cp; const float* bp;
    int HW, hw, rowlen, step;
    if (r < 6400) {
        cp = cls0 + (size_t)b * NCLS * 6400; bp = box0 + (size_t)b * 4 * 6400;
        HW = 6400; hw = r;        rowlen = 80; step = 8;
    } else if (r < 8000) {
        cp = cls1 + (size_t)b * NCLS * 1600; bp = box1 + (size_t)b * 4 * 1600;
        HW = 1600; hw = r - 6400; rowlen = 40; step = 16;
    } else {
        cp = cls2 + (size_t)b * NCLS * 400;  bp = box2 + (size_t)b * 4 * 400;
        HW = 400;  hw = r - 8000; rowlen = 20; step = 32;
    }

    __shared__ float s_m[4][4][64];             // [slice][anchor-in-quad][quad-lane]
    __shared__ int   s_c[4][4][64];

    // 20-class slice argmax (first-max: strict >, ascending class within slice)
    {
        const float* cps = cp + (size_t)(wv * 20) * HW + hw;
        float4 m = *(const float4*)cps;
        int c0 = wv * 20, c1 = c0, c2 = c0, c3 = c0;
#pragma unroll
        for (int c = 1; c < 20; ++c) {
            float4 v = *(const float4*)(cps + (size_t)c * HW);
            int cc = wv * 20 + c;
            if (v.x > m.x) { m.x = v.x; c0 = cc; }
            if (v.y > m.y) { m.y = v.y; c1 = cc; }
            if (v.z > m.z) { m.z = v.z; c2 = cc; }
            if (v.w > m.w) { m.w = v.w; c3 = cc; }
        }
        s_m[wv][0][lane] = m.x; s_c[wv][0][lane] = c0;
        s_m[wv][1][lane] = m.y; s_c[wv][1][lane] = c1;
        s_m[wv][2][lane] = m.z; s_c[wv][2][lane] = c2;
        s_m[wv][3][lane] = m.w; s_c[wv][3][lane] = c3;
    }
    __syncthreads();

    if (wv == 0) {
        // combine slices in ascending-class order: strict > keeps first max
        float mm[4]; int cc[4];
#pragma unroll
        for (int j = 0; j < 4; ++j) {
            float mv = s_m[0][j][lane]; int cv = s_c[0][j][lane];
#pragma unroll
            for (int s = 1; s < 4; ++s) {
                float v = s_m[s][j][lane];
                if (v > mv) { mv = v; cv = s_c[s][j][lane]; }
            }
            mm[j] = mv; cc[j] = cv;
        }

        float4 L  = *(const float4*)(bp + hw);
        float4 T  = *(const float4*)(bp + HW + hw);
        float4 R  = *(const float4*)(bp + 2 * HW + hw);
        float4 Bo = *(const float4*)(bp + 3 * HW + hw);

        int h = hw / rowlen, w = hw - h * rowlen;   // w..w+3 stay in this row
        float gy  = (float)(h * step);
        float gx0 = (float)(w * step);
        float gx1 = gx0 + (float)step;
        float gx2 = gx1 + (float)step;
        float gx3 = gx2 + (float)step;

        int g = b * NANCHOR + r;
        float4 sc;
        sc.x = 1.0f / (1.0f + expf(-mm[0]));
        sc.y = 1.0f / (1.0f + expf(-mm[1]));
        sc.z = 1.0f / (1.0f + expf(-mm[2]));
        sc.w = 1.0f / (1.0f + expf(-mm[3]));
        *(float4*)(ws_scores + g) = sc;
        ws_boxes[g + 0] = make_float4(gx0 - L.x, gy - T.x, gx0 + R.x, gy + Bo.x);
        ws_boxes[g + 1] = make_float4(gx1 - L.y, gy - T.y, gx1 + R.y, gy + Bo.y);
        ws_boxes[g + 2] = make_float4(gx2 - L.z, gy - T.z, gx2 + R.z, gy + Bo.z);
        ws_boxes[g + 3] = make_float4(gx3 - L.w, gy - T.w, gx3 + R.w, gy + Bo.w);
        *(int4*)(ws_cls + g) = make_int4(cc[0], cc[1], cc[2], cc[3]);
    }
}

// ---------------------------------------------------------------------------
// helpers
// ---------------------------------------------------------------------------
__device__ __forceinline__ u64 shfl_xor_u64(u64 v, int m) {
    u32 lo = (u32)v, hi = (u32)(v >> 32);
    lo = (u32)__shfl_xor((int)lo, m, 64);
    hi = (u32)__shfl_xor((int)hi, m, 64);
    return ((u64)hi << 32) | (u64)lo;
}

__device__ __forceinline__ u64 readlane_u64(u64 v, int l) {
    u32 lo = (u32)v, hi = (u32)(v >> 32);
    lo = (u32)__builtin_amdgcn_readlane((int)lo, l);
    hi = (u32)__builtin_amdgcn_readlane((int)hi, l);
    return ((u64)hi << 32) | (u64)lo;
}

// inclusive suffix sum over sh[0..1023]; 3 barriers total.
__device__ __forceinline__ void suffix_scan_1024(int* sh, int* swsum, int* swadd) {
    const int tid = threadIdx.x, lane = tid & 63, wv = tid >> 6;
    int s = sh[tid];
#pragma unroll
    for (int off = 1; off < 64; off <<= 1) {
        int u = __shfl_down(s, off, 64);
        if (lane + off < 64) s += u;
    }
    if (lane == 0) swsum[wv] = s;          // wave total = suffix at lane 0
    __syncthreads();
    if (tid < 64) {
        int t = (lane < 16) ? swsum[lane] : 0;
#pragma unroll
        for (int off = 1; off < 16; off <<= 1) {
            int u = __shfl_down(t, off, 64);
            if (lane + off < 64) t += u;
        }
        int ab = __shfl_down(t, 1, 64);    // suffix of waves strictly above
        if (lane < 16) swadd[lane] = (lane == 15) ? 0 : ab;
    }
    __syncthreads();
    sh[tid] = s + swadd[wv];
    __syncthreads();
}

// ---------------------------------------------------------------------------
// Kernel 2: per-image radix-select + sort. Score bits live in per-thread
// registers (each thread re-reads exactly the elements it loaded: a=tid+k*NT,
// static unrolled indexing). cnt<=1024: single-wave zero-barrier register
// bitonic. cnt>1024 (tie-storm): LDS bitonic fallback on 2048.
// ---------------------------------------------------------------------------
__global__ __launch_bounds__(NT) void select_sort_kernel(
        const float* __restrict__ ws_scores, const float4* __restrict__ ws_boxes,
        const int* __restrict__ ws_cls, u64* __restrict__ ws_keys,
        float* __restrict__ ws_sx1, float* __restrict__ ws_sy1,
        float* __restrict__ ws_sx2, float* __restrict__ ws_sy2,
        float* __restrict__ ws_sar) {
    const int b = blockIdx.x;
    const int tid = threadIdx.x;

    __shared__ int s_hist[1024];
    __shared__ u64 s_key[2048];
    __shared__ int s_wsum[16], s_wadd[16];
    __shared__ int s_C, s_base, s_cnt;
    __shared__ u32 s_thresh;

    const float* sc = ws_scores + (size_t)b * NANCHOR;

    s_hist[tid] = 0;
    s_key[tid] = 0ULL;
    s_key[tid + 1024] = 0ULL;
    if (tid == 0) s_cnt = 0;
    __syncthreads();

    // ---- pass 1: coarse histogram on bits [29:20]; cache bits in registers
    u32 sb[9];
#pragma unroll
    for (int k = 0; k < 9; ++k) {
        int a = tid + k * NT;
        if (a < NANCHOR) {
            u32 x = __float_as_uint(sc[a]);
            sb[k] = x;
            atomicAdd(&s_hist[x >> 20], 1);
        } else sb[k] = 0;
    }
    __syncthreads();
    suffix_scan_1024(s_hist, s_wsum, s_wadd);
    {
        int sfx = s_hist[tid];
        int nxt = (tid < 1023) ? s_hist[tid + 1] : 0;
        if (sfx >= PRE && (tid == 1023 || nxt < PRE)) { s_C = tid; s_base = nxt; }
    }
    __syncthreads();
    const int C = s_C, base = s_base;
    s_hist[tid] = 0;
    __syncthreads();

    // ---- pass 2: fine histogram on bits [19:10] within coarse bin C
#pragma unroll
    for (int k = 0; k < 9; ++k) {
        int a = tid + k * NT;
        if (a < NANCHOR && (int)(sb[k] >> 20) == C)
            atomicAdd(&s_hist[(sb[k] >> 10) & 1023], 1);
    }
    __syncthreads();
    suffix_scan_1024(s_hist, s_wsum, s_wadd);
    {
        int sfx = base + s_hist[tid];
        int nxt = base + ((tid < 1023) ? s_hist[tid + 1] : 0);
        if (sfx >= PRE && (tid == 1023 || nxt < PRE))
            s_thresh = ((u32)C << 20) | ((u32)tid << 10);
    }
    __syncthreads();
    const u32 thresh = s_thresh;

    // ---- compaction
#pragma unroll
    for (int k = 0; k < 9; ++k) {
        int a = tid + k * NT;
        if (a < NANCHOR && sb[k] >= thresh) {
            int pos = atomicAdd(&s_cnt, 1);
            if (pos < 2048)
                s_key[pos] = ((u64)sb[k] << 14) | (u64)(NANCHOR - 1 - a);
        }
    }
    __syncthreads();
    const int cnt = s_cnt;

    if (cnt > 1024) {
        // ---- fallback: LDS bitonic on 2048 (wave-sync for j<=32)
        bool prevBig = false;
        for (int k = 2; k <= 2048; k <<= 1) {
            for (int j = k >> 1; j > 0; j >>= 1) {
                const bool big = (j >= 64);
                if (big || prevBig) __syncthreads();
                else __builtin_amdgcn_wave_barrier();
                for (int i = tid; i < 2048; i += NT) {
                    int ixj = i ^ j;
                    if (ixj > i) {
                        u64 va = s_key[i], vb = s_key[ixj];
                        bool desc = ((i & k) == 0);
                        if (desc ? (va < vb) : (va > vb)) { s_key[i] = vb; s_key[ixj] = va; }
                    }
                }
                prevBig = big;
            }
        }
        __syncthreads();
    } else {
        // ---- single-wave register bitonic over 1024 keys, no barriers
        if (tid < 64) {
            const int lane = tid;
            u64 v[16];
#pragma unroll
            for (int r = 0; r < 16; ++r) v[r] = s_key[(r << 6) | lane];

#define CE_REG(ra, rb, DESC) { u64 a_ = v[(ra)], b_ = v[(rb)];                        \
            if ((DESC) ? (a_ < b_) : (a_ > b_)) { v[(ra)] = b_; v[(rb)] = a_; } }
#define CE_SHFL(rr_, jj_, DESC) { u64 a_ = v[(rr_)]; u64 p_ = shfl_xor_u64(a_, (jj_)); \
            bool up_ = ((lane & (jj_)) == 0); bool km_ = ((DESC) == up_);              \
            bool pg_ = (p_ > a_); v[(rr_)] = (km_ == pg_) ? p_ : a_; }

#pragma unroll
            for (int kl = 1; kl <= 10; ++kl) {
                const int K = 1 << kl;
#pragma unroll
                for (int js = 10; js >= 0; --js) {
                    if (js > kl - 1) continue;
                    const int j = 1 << js;
                    if (j >= 64) {
                        const int jr = j >> 6;
#pragma unroll
                        for (int r = 0; r < 16; ++r) {
                            if ((r & jr) == 0) {
                                const bool desc = ((r & (K >> 6)) == 0);
                                CE_REG(r, r | jr, desc);
                            }
                        }
                    } else {
#pragma unroll
                        for (int r = 0; r < 16; ++r) {
                            if (K >= 64) {
                                const bool desc = ((r & (K >> 6)) == 0);
                                CE_SHFL(r, j, desc);
                            } else {
                                CE_SHFL(r, j, ((lane & K) == 0));
                            }
                        }
                    }
                }
            }
#undef CE_REG
#undef CE_SHFL

#pragma unroll
            for (int r = 0; r < 16; ++r) s_key[(r << 6) | lane] = v[r];
        }
        __syncthreads();
    }

    // ---- write sorted keys + class-offset boxes/areas (slots 0..1023)
    {
        u64 key = s_key[tid];
        ws_keys[(b << 10) + tid] = key;
        int idx = (NANCHOR - 1) - (int)(key & 16383ULL);
        float4 bx = ws_boxes[(size_t)b * NANCHOR + idx];
        int c = ws_cls[(size_t)b * NANCHOR + idx];
        float off = (float)c * 4096.0f;
        float x1 = bx.x + off, y1 = bx.y + off, x2 = bx.z + off, y2 = bx.w + off;
        int o = (b << 10) + tid;
        ws_sx1[o] = x1; ws_sy1[o] = y1; ws_sx2[o] = x2; ws_sy2[o] = y2;
        ws_sar[o] = fmaxf(x2 - x1, 0.0f) * fmaxf(y2 - y1, 0.0f);
    }
}

// ---------------------------------------------------------------------------
// Kernel 3: suppression bitmap. Block = (image, 64-row tile); thread = (row, word).
// bits[r][w] bit k = (IoU(r, w*64+k) > 0.5) && (w*64+k > r) && (w*64+k < 1000).
// Also writes the diagonal word (w == r>>6) to a compact per-row array.
// ---------------------------------------------------------------------------
__global__ __launch_bounds__(1024) void iou_bits_kernel(
        const float* __restrict__ ws_sx1, const float* __restrict__ ws_sy1,
        const float* __restrict__ ws_sx2, const float* __restrict__ ws_sy2,
        const float* __restrict__ ws_sar,
        u64* __restrict__ ws_bits, u64* __restrict__ ws_diag) {
    const int blk = blockIdx.x;
    const int b = blk >> 4, tile = blk & 15;
    const int tid = threadIdx.x;

    __shared__ float sx1[1024], sy1[1024], sx2[1024], sy2[1024], sar[1024];
    {
        int o = (b << 10) + tid;
        sx1[tid] = ws_sx1[o]; sy1[tid] = ws_sy1[o];
        sx2[tid] = ws_sx2[o]; sy2[tid] = ws_sy2[o];
        sar[tid] = ws_sar[o];
    }
    __syncthreads();

    const int rl = tid & 63, w = tid >> 6;
    const int r = (tile << 6) + rl;
    u64 bits = 0ULL;
    if (r < 1000 && w >= tile) {            // words below the diagonal are all-zero
        float xi1 = sx1[r], yi1 = sy1[r], xi2 = sx2[r], yi2 = sy2[r], ai = sar[r];
        const int jbase = w << 6;
#pragma unroll 8
        for (int kb = 0; kb < 64; ++kb) {
            int j = jbase + kb;             // broadcast LDS reads across the wave
            float lx = fmaxf(xi1, sx1[j]);
            float ly = fmaxf(yi1, sy1[j]);
            float rx = fminf(xi2, sx2[j]);
            float ry = fminf(yi2, sy2[j]);
            float wx = fmaxf(rx - lx, 0.0f);
            float wy = fmaxf(ry - ly, 0.0f);
            float inter = wx * wy;
            float iou = inter / (ai + sar[j] - inter + 1e-7f);
            bits |= (iou > 0.5f) ? (1ULL << kb) : 0ULL;
        }
        u64 mlow;                            // keep only j > r
        if (w == tile) {
            int bpos = r & 63;
            mlow = (bpos == 63) ? 0ULL : (~0ULL << (bpos + 1));
        } else mlow = ~0ULL;
        u64 mhigh = (jbase + 64 <= 1000) ? ~0ULL : ((1ULL << (1000 - jbase)) - 1ULL);
        bits &= mlow & mhigh;
    }
    ws_bits[((size_t)b << 14) + ((size_t)r << 4) + w] = bits;
    if (w == tile) ws_diag[(b << 10) + r] = bits;
}

// ---------------------------------------------------------------------------
// Kernel 4: per-image barrier-free greedy scan over the bitmap (wave 0 of a
// 128-thread block), then output.
// ---------------------------------------------------------------------------
__global__ __launch_bounds__(128) void nms_scan_kernel(
        const u64* __restrict__ ws_bits, const u64* __restrict__ ws_diag,
        const u64* __restrict__ ws_keys, const float4* __restrict__ ws_boxes,
        const int* __restrict__ ws_cls, float* __restrict__ out) {
    const int b = blockIdx.x;
    const int tid = threadIdx.x;

    __shared__ int s_keep[MAXDET];
    __shared__ int s_nk;

    if (tid < 64) {
        const int lane = tid;
        const u64* bits = ws_bits + ((size_t)b << 14);
        const u64* diag = ws_diag + ((size_t)b << 10);
        int nkept = 0;
        for (int wi = 0; wi < 16 && nkept < MAXDET; ++wi) {
            const int wbase = wi << 6;
            // state of this word from rows kept in earlier words
            u64 acc = 0ULL;
            if (lane < nkept)       acc  = bits[((size_t)s_keep[lane] << 4) + wi];
            if (lane + 64 < nkept)  acc |= bits[((size_t)s_keep[lane + 64] << 4) + wi];
#pragma unroll
            for (int off = 32; off > 0; off >>= 1) acc |= shfl_xor_u64(acc, off);
            u64 cur = acc;                          // uniform across the wave
            u64 rw = diag[wbase + lane];            // lane l holds word wi of row wbase+l
            const int nb = (wbase + 64 <= 1000) ? 64 : (1000 - wbase);
            for (int bit = 0; bit < nb; ++bit) {
                if (!((cur >> bit) & 1ULL)) {
                    if (lane == 0) s_keep[nkept] = wbase + bit;
                    nkept++;
                    if (nkept >= MAXDET) break;
                    cur |= readlane_u64(rw, bit);   // suppress within this word
                }
            }
        }
        if (lane == 0) s_nk = nkept;
    }
    __syncthreads();

    const int nk = s_nk;
    if (tid < MAXDET) {
        float* o = out + ((size_t)b * MAXDET + tid) * 5;
        float* oc = out + (size_t)NB * MAXDET * 5 + (size_t)b * MAXDET + tid;
        if (tid < nk) {
            int rank = s_keep[tid];
            u64 key = ws_keys[(b << 10) + rank];
            int idx = (NANCHOR - 1) - (int)(key & 16383ULL);
            float score = __uint_as_float((u32)(key >> 14));
            float4 bx = ws_boxes[(size_t)b * NANCHOR + idx];
            int c = ws_cls[(size_t)b * NANCHOR + idx];
            o[0] = bx.x; o[1] = bx.y; o[2] = bx.z; o[3] = bx.w; o[4] = score;
            *oc = (float)c;
        } else {
            o[0] = 0.0f; o[1] = 0.0f; o[2] = 0.0f; o[3] = 0.0f; o[4] = 0.0f;
            *oc = -1.0f;
        }
    }
}

extern "C" void kernel_launch(void* const* d_in, const int* in_sizes, int n_in,
                              void* d_out, int out_size, void* d_ws, size_t ws_size,
                              hipStream_t stream) {
    const float* cls0 = (const float*)d_in[0];
    const float* box0 = (const float*)d_in[1];
    const float* cls1 = (const float*)d_in[2];
    const float* box1 = (const float*)d_in[3];
    const float* cls2 = (const float*)d_in[4];
    const float* box2 = (const float*)d_in[5];

    float* ws = (float*)d_ws;
    float* ws_scores = ws;                                    // 268800 f32
    float4* ws_boxes = (float4*)(ws + NB * NANCHOR);          // 268800 float4
    int* ws_cls = (int*)(ws + (size_t)NB * NANCHOR * 5);      // 268800 int
    float* base6 = ws + (size_t)NB * NANCHOR * 6;             // byte 6,451,200
    u64* ws_keys = (u64*)base6;                               // 32*1024 u64
    float* ws_sx1 = base6 + 65536;                            // after 262144 B
    float* ws_sy1 = ws_sx1 + NB * 1024;
    float* ws_sx2 = ws_sy1 + NB * 1024;
    float* ws_sy2 = ws_sx2 + NB * 1024;
    float* ws_sar = ws_sy2 + NB * 1024;
    u64* ws_bits = (u64*)(ws_sar + NB * 1024);                // 32*1024*16 u64 = 4 MB
    u64* ws_diag = ws_bits + (size_t)NB * 1024 * 16;          // 32*1024 u64

    int nquads = NB * (NANCHOR / 4);            // 67200 = 1050 * 64 exactly
    decode_kernel<<<nquads / 64, 256, 0, stream>>>(
        cls0, box0, cls1, box1, cls2, box2, ws_scores, ws_boxes, ws_cls);

    select_sort_kernel<<<NB, NT, 0, stream>>>(ws_scores, ws_boxes, ws_cls, ws_keys,
                                              ws_sx1, ws_sy1, ws_sx2, ws_sy2, ws_sar);

    iou_bits_kernel<<<NB * 16, 1024, 0, stream>>>(ws_sx1, ws_sy1, ws_sx2, ws_sy2, ws_sar,
                                                  ws_bits, ws_diag);

    nms_scan_kernel<<<NB, 128, 0, stream>>>(ws_bits, ws_diag, ws_keys, ws_boxes, ws_cls,
                                            (float*)d_out);
}

// Round 5
// 184.304 us; speedup vs baseline: 1.0938x; 1.0074x over previous
//
#include <hip/hip_runtime.h>

typedef unsigned int u32;
typedef unsigned long long u64;

#define NB 32
#define NCLS 80
#define NANCHOR 8400
#define PRE 1000
#define MAXDET 100
#define NT 1024

// ---------------------------------------------------------------------------
// Kernel 1: decode all levels. Block = 64 quads (256 anchors); the 4 waves of
// the block split the 80-class argmax into 20-class slices (wave w -> classes
// [20w,20w+20)), each lane owning one quad with float4 (16 B) loads. Partials
// reduce through LDS; wave 0 finishes (sigmoid + box decode + stores).
// Grid = 1050 blocks -> ~4 blocks/CU, so HBM latency is TLP-hidden.
// ---------------------------------------------------------------------------
__global__ __launch_bounds__(256) void decode_kernel(
        const float* __restrict__ cls0, const float* __restrict__ box0,
        const float* __restrict__ cls1, const float* __restrict__ box1,
        const float* __restrict__ cls2, const float* __restrict__ box2,
        float* __restrict__ ws_scores, float4* __restrict__ ws_boxes,
        int* __restrict__ ws_cls) {
    const int NQ = NANCHOR / 4;                 // 2100 quads per image
    const int lane = threadIdx.x & 63;
    const int wv = threadIdx.x >> 6;            // class slice 0..3
    const int q = blockIdx.x * 64 + lane;       // quad id (grid is exact: 1050*64)
    int b = q / NQ;
    int r = (q - b * NQ) * 4;                   // first anchor of the quad

    const float* cp; const float* bp;
    int HW, hw, rowlen, step;
    if (r < 6400) {
        cp = cls0 + (size_t)b * NCLS * 6400; bp = box0 + (size_t)b * 4 * 6400;
        HW = 6400; hw = r;        rowlen = 80; step = 8;
    } else if (r < 8000) {
        cp = cls1 + (size_t)b * NCLS * 1600; bp = box1 + (size_t)b * 4 * 1600;
        HW = 1600; hw = r - 6400; rowlen = 40; step = 16;
    } else {
        cp = cls2 + (size_t)b * NCLS * 400;  bp = box2 + (size_t)b * 4 * 400;
        HW = 400;  hw = r - 8000; rowlen = 20; step = 32;
    }

    __shared__ float s_m[4][4][64];             // [slice][anchor-in-quad][quad-lane]
    __shared__ int   s_c[4][4][64];

    // 20-class slice argmax (first-max: strict >, ascending class within slice)
    {
        const float* cps = cp + (size_t)(wv * 20) * HW + hw;
        float4 m = *(const float4*)cps;
        int c0 = wv * 20, c1 = c0, c2 = c0, c3 = c0;
#pragma unroll
        for (int c = 1; c < 20; ++c) {
            float4 v = *(const float4*)(cps + (size_t)c * HW);
            int cc = wv * 20 + c;
            if (v.x > m.x) { m.x = v.x; c0 = cc; }
            if (v.y > m.y) { m.y = v.y; c1 = cc; }
            if (v.z > m.z) { m.z = v.z; c2 = cc; }
            if (v.w > m.w) { m.w = v.w; c3 = cc; }
        }
        s_m[wv][0][lane] = m.x; s_c[wv][0][lane] = c0;
        s_m[wv][1][lane] = m.y; s_c[wv][1][lane] = c1;
        s_m[wv][2][lane] = m.z; s_c[wv][2][lane] = c2;
        s_m[wv][3][lane] = m.w; s_c[wv][3][lane] = c3;
    }
    __syncthreads();

    if (wv == 0) {
        // combine slices in ascending-class order: strict > keeps first max
        float mm[4]; int cc[4];
#pragma unroll
        for (int j = 0; j < 4; ++j) {
            float mv = s_m[0][j][lane]; int cv = s_c[0][j][lane];
#pragma unroll
            for (int s = 1; s < 4; ++s) {
                float v = s_m[s][j][lane];
                if (v > mv) { mv = v; cv = s_c[s][j][lane]; }
            }
            mm[j] = mv; cc[j] = cv;
        }

        float4 L  = *(const float4*)(bp + hw);
        float4 T  = *(const float4*)(bp + HW + hw);
        float4 R  = *(const float4*)(bp + 2 * HW + hw);
        float4 Bo = *(const float4*)(bp + 3 * HW + hw);

        int h = hw / rowlen, w = hw - h * rowlen;   // w..w+3 stay in this row
        float gy  = (float)(h * step);
        float gx0 = (float)(w * step);
        float gx1 = gx0 + (float)step;
        float gx2 = gx1 + (float)step;
        float gx3 = gx2 + (float)step;

        int g = b * NANCHOR + r;
        float4 sc;
        sc.x = 1.0f / (1.0f + expf(-mm[0]));
        sc.y = 1.0f / (1.0f + expf(-mm[1]));
        sc.z = 1.0f / (1.0f + expf(-mm[2]));
        sc.w = 1.0f / (1.0f + expf(-mm[3]));
        *(float4*)(ws_scores + g) = sc;
        ws_boxes[g + 0] = make_float4(gx0 - L.x, gy - T.x, gx0 + R.x, gy + Bo.x);
        ws_boxes[g + 1] = make_float4(gx1 - L.y, gy - T.y, gx1 + R.y, gy + Bo.y);
        ws_boxes[g + 2] = make_float4(gx2 - L.z, gy - T.z, gx2 + R.z, gy + Bo.z);
        ws_boxes[g + 3] = make_float4(gx3 - L.w, gy - T.w, gx3 + R.w, gy + Bo.w);
        *(int4*)(ws_cls + g) = make_int4(cc[0], cc[1], cc[2], cc[3]);
    }
}

// ---------------------------------------------------------------------------
// helpers
// ---------------------------------------------------------------------------
__device__ __forceinline__ u64 shfl_xor_u64(u64 v, int m) {
    u32 lo = (u32)v, hi = (u32)(v >> 32);
    lo = (u32)__shfl_xor((int)lo, m, 64);
    hi = (u32)__shfl_xor((int)hi, m, 64);
    return ((u64)hi << 32) | (u64)lo;
}

__device__ __forceinline__ u64 readlane_u64(u64 v, int l) {
    u32 lo = (u32)v, hi = (u32)(v >> 32);
    lo = (u32)__builtin_amdgcn_readlane((int)lo, l);
    hi = (u32)__builtin_amdgcn_readlane((int)hi, l);
    return ((u64)hi << 32) | (u64)lo;
}

// inclusive suffix sum over sh[0..1023]; 3 barriers total.
__device__ __forceinline__ void suffix_scan_1024(int* sh, int* swsum, int* swadd) {
    const int tid = threadIdx.x, lane = tid & 63, wv = tid >> 6;
    int s = sh[tid];
#pragma unroll
    for (int off = 1; off < 64; off <<= 1) {
        int u = __shfl_down(s, off, 64);
        if (lane + off < 64) s += u;
    }
    if (lane == 0) swsum[wv] = s;          // wave total = suffix at lane 0
    __syncthreads();
    if (tid < 64) {
        int t = (lane < 16) ? swsum[lane] : 0;
#pragma unroll
        for (int off = 1; off < 16; off <<= 1) {
            int u = __shfl_down(t, off, 64);
            if (lane + off < 64) t += u;
        }
        int ab = __shfl_down(t, 1, 64);    // suffix of waves strictly above
        if (lane < 16) swadd[lane] = (lane == 15) ? 0 : ab;
    }
    __syncthreads();
    sh[tid] = s + swadd[wv];
    __syncthreads();
}

// ---------------------------------------------------------------------------
// Kernel 2: per-image radix-select + counting-rank ordering.
// cnt<=1024 (typical): every key is distinct (idx tiebreak; pads remapped to
// distinct tiny values), so rank = #{keys > mine} is a permutation. Each of
// the 1024 threads streams all 1024 keys from LDS (wave-uniform broadcast
// reads) and scatters its key to s_key[rank]. 4 barriers, no bitonic.
// cnt>1024 (tie-storm): verified LDS bitonic fallback on 2048.
// ---------------------------------------------------------------------------
__global__ __launch_bounds__(NT) void select_sort_kernel(
        const float* __restrict__ ws_scores, const float4* __restrict__ ws_boxes,
        const int* __restrict__ ws_cls, u64* __restrict__ ws_keys,
        float* __restrict__ ws_sx1, float* __restrict__ ws_sy1,
        float* __restrict__ ws_sx2, float* __restrict__ ws_sy2,
        float* __restrict__ ws_sar) {
    const int b = blockIdx.x;
    const int tid = threadIdx.x;

    __shared__ int s_hist[1024];
    __shared__ u64 s_key[2048];
    __shared__ int s_wsum[16], s_wadd[16];
    __shared__ int s_C, s_base, s_cnt;
    __shared__ u32 s_thresh;

    const float* sc = ws_scores + (size_t)b * NANCHOR;

    s_hist[tid] = 0;
    s_key[tid] = 0ULL;
    s_key[tid + 1024] = 0ULL;
    if (tid == 0) s_cnt = 0;
    __syncthreads();

    // ---- pass 1: coarse histogram on bits [29:20]; cache bits in registers
    u32 sb[9];
#pragma unroll
    for (int k = 0; k < 9; ++k) {
        int a = tid + k * NT;
        if (a < NANCHOR) {
            u32 x = __float_as_uint(sc[a]);
            sb[k] = x;
            atomicAdd(&s_hist[x >> 20], 1);
        } else sb[k] = 0;
    }
    __syncthreads();
    suffix_scan_1024(s_hist, s_wsum, s_wadd);
    {
        int sfx = s_hist[tid];
        int nxt = (tid < 1023) ? s_hist[tid + 1] : 0;
        if (sfx >= PRE && (tid == 1023 || nxt < PRE)) { s_C = tid; s_base = nxt; }
    }
    __syncthreads();
    const int C = s_C, base = s_base;
    s_hist[tid] = 0;
    __syncthreads();

    // ---- pass 2: fine histogram on bits [19:10] within coarse bin C
#pragma unroll
    for (int k = 0; k < 9; ++k) {
        int a = tid + k * NT;
        if (a < NANCHOR && (int)(sb[k] >> 20) == C)
            atomicAdd(&s_hist[(sb[k] >> 10) & 1023], 1);
    }
    __syncthreads();
    suffix_scan_1024(s_hist, s_wsum, s_wadd);
    {
        int sfx = base + s_hist[tid];
        int nxt = base + ((tid < 1023) ? s_hist[tid + 1] : 0);
        if (sfx >= PRE && (tid == 1023 || nxt < PRE))
            s_thresh = ((u32)C << 20) | ((u32)tid << 10);
    }
    __syncthreads();
    const u32 thresh = s_thresh;

    // ---- compaction
#pragma unroll
    for (int k = 0; k < 9; ++k) {
        int a = tid + k * NT;
        if (a < NANCHOR && sb[k] >= thresh) {
            int pos = atomicAdd(&s_cnt, 1);
            if (pos < 2048)
                s_key[pos] = ((u64)sb[k] << 14) | (u64)(NANCHOR - 1 - a);
        }
    }
    __syncthreads();
    const int cnt = s_cnt;

    if (cnt > 1024) {
        // ---- fallback: LDS bitonic on 2048 (wave-sync for j<=32)
        bool prevBig = false;
        for (int k = 2; k <= 2048; k <<= 1) {
            for (int j = k >> 1; j > 0; j >>= 1) {
                const bool big = (j >= 64);
                if (big || prevBig) __syncthreads();
                else __builtin_amdgcn_wave_barrier();
                for (int i = tid; i < 2048; i += NT) {
                    int ixj = i ^ j;
                    if (ixj > i) {
                        u64 va = s_key[i], vb = s_key[ixj];
                        bool desc = ((i & k) == 0);
                        if (desc ? (va < vb) : (va > vb)) { s_key[i] = vb; s_key[ixj] = va; }
                    }
                }
                prevBig = big;
            }
        }
        __syncthreads();
    } else {
        // ---- counting-rank scatter (all keys distinct)
        // pads -> distinct tiny keys: real keys have score bits >= thresh >= 1
        // (thresh==0 implies cnt==8400 -> fallback), so (key >> 14) >= 1 and any
        // pad value (u64)tid <= 1023 < 2^14 sorts strictly below all real keys.
        if (tid >= cnt) s_key[tid] = (u64)tid;
        __syncthreads();
        const u64 my = s_key[tid];
        int rank = 0;
#pragma unroll 4
        for (int j = 0; j < 1024; j += 4) {
            u64 k0 = s_key[j + 0], k1 = s_key[j + 1];
            u64 k2 = s_key[j + 2], k3 = s_key[j + 3];
            rank += (int)(k0 > my) + (int)(k1 > my) + (int)(k2 > my) + (int)(k3 > my);
        }
        __syncthreads();
        s_key[rank] = my;      // permutation: no conflicts
        __syncthreads();
    }

    // ---- write sorted keys + class-offset boxes/areas (slots 0..1023)
    {
        u64 key = s_key[tid];
        ws_keys[(b << 10) + tid] = key;
        int idx = (NANCHOR - 1) - (int)(key & 16383ULL);
        float4 bx = ws_boxes[(size_t)b * NANCHOR + idx];
        int c = ws_cls[(size_t)b * NANCHOR + idx];
        float off = (float)c * 4096.0f;
        float x1 = bx.x + off, y1 = bx.y + off, x2 = bx.z + off, y2 = bx.w + off;
        int o = (b << 10) + tid;
        ws_sx1[o] = x1; ws_sy1[o] = y1; ws_sx2[o] = x2; ws_sy2[o] = y2;
        ws_sar[o] = fmaxf(x2 - x1, 0.0f) * fmaxf(y2 - y1, 0.0f);
    }
}

// ---------------------------------------------------------------------------
// Kernel 3: suppression bitmap. Block = (image, 64-row tile); thread = (row, word).
// bits[r][w] bit k = (IoU(r, w*64+k) > 0.5) && (w*64+k > r) && (w*64+k < 1000).
// Also writes the diagonal word (w == r>>6) to a compact per-row array.
// ---------------------------------------------------------------------------
__global__ __launch_bounds__(1024) void iou_bits_kernel(
        const float* __restrict__ ws_sx1, const float* __restrict__ ws_sy1,
        const float* __restrict__ ws_sx2, const float* __restrict__ ws_sy2,
        const float* __restrict__ ws_sar,
        u64* __restrict__ ws_bits, u64* __restrict__ ws_diag) {
    const int blk = blockIdx.x;
    const int b = blk >> 4, tile = blk & 15;
    const int tid = threadIdx.x;

    __shared__ float sx1[1024], sy1[1024], sx2[1024], sy2[1024], sar[1024];
    {
        int o = (b << 10) + tid;
        sx1[tid] = ws_sx1[o]; sy1[tid] = ws_sy1[o];
        sx2[tid] = ws_sx2[o]; sy2[tid] = ws_sy2[o];
        sar[tid] = ws_sar[o];
    }
    __syncthreads();

    const int rl = tid & 63, w = tid >> 6;
    const int r = (tile << 6) + rl;
    u64 bits = 0ULL;
    if (r < 1000 && w >= tile) {            // words below the diagonal are all-zero
        float xi1 = sx1[r], yi1 = sy1[r], xi2 = sx2[r], yi2 = sy2[r], ai = sar[r];
        const int jbase = w << 6;
#pragma unroll 8
        for (int kb = 0; kb < 64; ++kb) {
            int j = jbase + kb;             // broadcast LDS reads across the wave
            float lx = fmaxf(xi1, sx1[j]);
            float ly = fmaxf(yi1, sy1[j]);
            float rx = fminf(xi2, sx2[j]);
            float ry = fminf(yi2, sy2[j]);
            float wx = fmaxf(rx - lx, 0.0f);
            float wy = fmaxf(ry - ly, 0.0f);
            float inter = wx * wy;
            float iou = inter / (ai + sar[j] - inter + 1e-7f);
            bits |= (iou > 0.5f) ? (1ULL << kb) : 0ULL;
        }
        u64 mlow;                            // keep only j > r
        if (w == tile) {
            int bpos = r & 63;
            mlow = (bpos == 63) ? 0ULL : (~0ULL << (bpos + 1));
        } else mlow = ~0ULL;
        u64 mhigh = (jbase + 64 <= 1000) ? ~0ULL : ((1ULL << (1000 - jbase)) - 1ULL);
        bits &= mlow & mhigh;
    }
    ws_bits[((size_t)b << 14) + ((size_t)r << 4) + w] = bits;
    if (w == tile) ws_diag[(b << 10) + r] = bits;
}

// ---------------------------------------------------------------------------
// Kernel 4: per-image barrier-free greedy scan over the bitmap (wave 0 of a
// 128-thread block), then output.
// ---------------------------------------------------------------------------
__global__ __launch_bounds__(128) void nms_scan_kernel(
        const u64* __restrict__ ws_bits, const u64* __restrict__ ws_diag,
        const u64* __restrict__ ws_keys, const float4* __restrict__ ws_boxes,
        const int* __restrict__ ws_cls, float* __restrict__ out) {
    const int b = blockIdx.x;
    const int tid = threadIdx.x;

    __shared__ int s_keep[MAXDET];
    __shared__ int s_nk;

    if (tid < 64) {
        const int lane = tid;
        const u64* bits = ws_bits + ((size_t)b << 14);
        const u64* diag = ws_diag + ((size_t)b << 10);
        int nkept = 0;
        for (int wi = 0; wi < 16 && nkept < MAXDET; ++wi) {
            const int wbase = wi << 6;
            // state of this word from rows kept in earlier words
            u64 acc = 0ULL;
            if (lane < nkept)       acc  = bits[((size_t)s_keep[lane] << 4) + wi];
            if (lane + 64 < nkept)  acc |= bits[((size_t)s_keep[lane + 64] << 4) + wi];
#pragma unroll
            for (int off = 32; off > 0; off >>= 1) acc |= shfl_xor_u64(acc, off);
            u64 cur = acc;                          // uniform across the wave
            u64 rw = diag[wbase + lane];            // lane l holds word wi of row wbase+l
            const int nb = (wbase + 64 <= 1000) ? 64 : (1000 - wbase);
            for (int bit = 0; bit < nb; ++bit) {
                if (!((cur >> bit) & 1ULL)) {
                    if (lane == 0) s_keep[nkept] = wbase + bit;
                    nkept++;
                    if (nkept >= MAXDET) break;
                    cur |= readlane_u64(rw, bit);   // suppress within this word
                }
            }
        }
        if (lane == 0) s_nk = nkept;
    }
    __syncthreads();

    const int nk = s_nk;
    if (tid < MAXDET) {
        float* o = out + ((size_t)b * MAXDET + tid) * 5;
        float* oc = out + (size_t)NB * MAXDET * 5 + (size_t)b * MAXDET + tid;
        if (tid < nk) {
            int rank = s_keep[tid];
            u64 key = ws_keys[(b << 10) + rank];
            int idx = (NANCHOR - 1) - (int)(key & 16383ULL);
            float score = __uint_as_float((u32)(key >> 14));
            float4 bx = ws_boxes[(size_t)b * NANCHOR + idx];
            int c = ws_cls[(size_t)b * NANCHOR + idx];
            o[0] = bx.x; o[1] = bx.y; o[2] = bx.z; o[3] = bx.w; o[4] = score;
            *oc = (float)c;
        } else {
            o[0] = 0.0f; o[1] = 0.0f; o[2] = 0.0f; o[3] = 0.0f; o[4] = 0.0f;
            *oc = -1.0f;
        }
    }
}

extern "C" void kernel_launch(void* const* d_in, const int* in_sizes, int n_in,
                              void* d_out, int out_size, void* d_ws, size_t ws_size,
                              hipStream_t stream) {
    const float* cls0 = (const float*)d_in[0];
    const float* box0 = (const float*)d_in[1];
    const float* cls1 = (const float*)d_in[2];
    const float* box1 = (const float*)d_in[3];
    const float* cls2 = (const float*)d_in[4];
    const float* box2 = (const float*)d_in[5];

    float* ws = (float*)d_ws;
    float* ws_scores = ws;                                    // 268800 f32
    float4* ws_boxes = (float4*)(ws + NB * NANCHOR);          // 268800 float4
    int* ws_cls = (int*)(ws + (size_t)NB * NANCHOR * 5);      // 268800 int
    float* base6 = ws + (size_t)NB * NANCHOR * 6;             // byte 6,451,200
    u64* ws_keys = (u64*)base6;                               // 32*1024 u64
    float* ws_sx1 = base6 + 65536;                            // after 262144 B
    float* ws_sy1 = ws_sx1 + NB * 1024;
    float* ws_sx2 = ws_sy1 + NB * 1024;
    float* ws_sy2 = ws_sx2 + NB * 1024;
    float* ws_sar = ws_sy2 + NB * 1024;
    u64* ws_bits = (u64*)(ws_sar + NB * 1024);                // 32*1024*16 u64 = 4 MB
    u64* ws_diag = ws_bits + (size_t)NB * 1024 * 16;          // 32*1024 u64

    int nquads = NB * (NANCHOR / 4);            // 67200 = 1050 * 64 exactly
    decode_kernel<<<nquads / 64, 256, 0, stream>>>(
        cls0, box0, cls1, box1, cls2, box2, ws_scores, ws_boxes, ws_cls);

    select_sort_kernel<<<NB, NT, 0, stream>>>(ws_scores, ws_boxes, ws_cls, ws_keys,
                                              ws_sx1, ws_sy1, ws_sx2, ws_sy2, ws_sar);

    iou_bits_kernel<<<NB * 16, 1024, 0, stream>>>(ws_sx1, ws_sy1, ws_sx2, ws_sy2, ws_sar,
                                                  ws_bits, ws_diag);

    nms_scan_kernel<<<NB, 128, 0, stream>>>(ws_bits, ws_diag, ws_keys, ws_boxes, ws_cls,
                                            (float*)d_out);
}